// Round 11
// baseline (298.282 us; speedup 1.0000x reference)
//
#include <hip/hip_runtime.h>
#include <math.h>

#define NB    2048
#define NSEG  20
#define MAXIT 48
// LDS chunk layout: one 32-k chunk = 4 octet-blocks of BLKS shorts.
// BLKS = 128 data shorts (16 cols x 8 k) + 8 pad shorts = 136.
// cols 0..7 = bf16-hi of elems 0..7, cols 8..15 = bf16-lo of elems 0..7.
// Bank math: BLKS*2B = 272B = 68 dwords == 4 (mod 32); chunk stride 544*2/4 = 272 == 16 (mod 32).
#define CH    544
#define BLKS  136

typedef __attribute__((ext_vector_type(8))) short bf8_t;
typedef __attribute__((ext_vector_type(4))) float f32x4;

#define cA21 ((float)0.161)
#define cA31 ((float)-0.008480655492356989)
#define cA32 ((float)0.335480655492357)
#define cA41 ((float)2.8971530571054935)
#define cA42 ((float)-6.359448489975075)
#define cA43 ((float)4.3622954328695815)
#define cA51 ((float)5.325864828439257)
#define cA52 ((float)-11.748883564062828)
#define cA53 ((float)7.4955393428898365)
#define cA54 ((float)-0.09249506636175525)
#define cA61 ((float)5.86145544294642)
#define cA62 ((float)-12.92096931784711)
#define cA63 ((float)8.159367898576159)
#define cA64 ((float)-0.071584973281401)
#define cA65 ((float)-0.028269050394068383)
#define cB1  ((float)0.09646076681806523)
#define cB2  ((float)0.01)
#define cB3  ((float)0.4798896504144996)
#define cB4  ((float)1.379008574103742)
#define cB5  ((float)-3.290069515436081)
#define cB6  ((float)2.324710524099774)
#define cE1  ((float)-0.001780011052225777)
#define cE2  ((float)-0.0008164344596567469)
#define cE3  ((float)0.007880878010261995)
#define cE4  ((float)-0.1447110071732629)
#define cE5  ((float)0.5823571654525552)
#define cE6  ((float)-0.45808210592918697)
#define cE7  ((float)0.015151515151515152)

__device__ __forceinline__ void split2(float x, short &hi, short &lo) {
    // x ~= bf16(hi) + bf16(lo), truncation-based (x - hi is exact in fp32)
    unsigned u = __float_as_uint(x);
    hi = (short)(u >> 16);
    float r = x - __uint_as_float(u & 0xFFFF0000u);
    lo = (short)(__float_as_uint(r) >> 16);
}

// round-to-nearest-even bf16 (weights only: no lo-correction MFMA anymore,
// rne halves the representation error vs truncation)
__device__ __forceinline__ short bfr(float x) {
    unsigned u = __float_as_uint(x);
    unsigned r = u + 0x7FFFu + ((u >> 16) & 1u);
    return (short)(r >> 16);
}

__device__ __forceinline__ float softplus_f(float x) {
    float t = exp2f(-fabsf(x) * 1.442695040888963f);
    return fmaxf(x, 0.0f) + log2f(1.0f + t) * 0.6931471805599453f;
}

__device__ __forceinline__ unsigned pk(short a, short b) {
    return ((unsigned)(unsigned short)a) | (((unsigned)(unsigned short)b) << 16);
}

// x + x[lane^8] within each 16-lane row: DPP row_ror:8 (0x128).  Pure VALU.
// NOTE: apply BEFORE any esel-dependent register select (round-4 lesson).
__device__ __forceinline__ float fold8(float x) {
    int r = __builtin_amdgcn_update_dpp(__float_as_int(x), __float_as_int(x),
                                        0x128, 0xF, 0xF, false);
    return x + __int_as_float(r);
}

// 512 threads = 8 waves; block processes 8 elements in lockstep.
// Round-11 = round-3 structure (best measured: 225.5 us) with SINGLE-bf16
// weights (rne): one MFMA per chunk instead of the hi/lo pair.  B still
// carries act hi+lo in the 16 columns, so result = W_rne*(argh+argl):
// activation precision full, weight error ~2^-9 systematic.
// Acts ping-pong through LDS in MFMA B-fragment layout; col e = hi(elem e),
// col e+8 = lo(elem e).  Fold via DPP ror8 sums the hi/lo partial products.
// Frag-layout (16x16x32 bf16): A[m=lane&15][k=32c+8*quad+jj]; B[k][n=lane&15];
// C/D: col=lane&15, row=4*quad+reg  (m89-verified).
__global__ __launch_bounds__(512)
void ode_kernel(const float* __restrict__ history,
                const float* __restrict__ W1, const float* __restrict__ b1,
                const float* __restrict__ W2, const float* __restrict__ b2,
                const float* __restrict__ W3, const float* __restrict__ b3,
                float* __restrict__ out)
{
    __shared__ alignas(16) short argB[2 * CH];
    __shared__ alignas(16) short h1B[4 * CH];
    __shared__ alignas(16) short h2B[4 * CH];
    __shared__ alignas(16) float kcur[8 * 68];   // [e][d], row-padded
    __shared__ int doneF[8];

    const int tid  = threadIdx.x;
    const int wave = tid >> 6, lane = tid & 63;
    const int quad = lane >> 4, col = lane & 15;
    const int jb   = 16 * wave + 4 * quad;       // this lane's D-row base (j or d)

    // ---- preload weight A-fragments (single rne bf16) ----
    bf8_t A1[2], A2[4], A3[4];
#pragma unroll
    for (int c = 0; c < 2; ++c) {
        const float* p = W1 + (size_t)(16 * wave + col) * 64 + 32 * c + 8 * quad;
        bf8_t h;
#pragma unroll
        for (int j = 0; j < 8; ++j) h[j] = bfr(p[j]);
        A1[c] = h;
    }
#pragma unroll
    for (int c = 0; c < 4; ++c) {
        const float* p = W2 + (size_t)(16 * wave + col) * 128 + 32 * c + 8 * quad;
        bf8_t h;
#pragma unroll
        for (int j = 0; j < 8; ++j) h[j] = bfr(p[j]);
        A2[c] = h;
    }
    f32x4 b3f = {0.f, 0.f, 0.f, 0.f};
    if (wave < 4) {
#pragma unroll
        for (int c = 0; c < 4; ++c) {
            const float* p = W3 + (size_t)(16 * wave + col) * 128 + 32 * c + 8 * quad;
            bf8_t h;
#pragma unroll
            for (int j = 0; j < 8; ++j) h[j] = bfr(p[j]);
            A3[c] = h;
        }
        b3f = *(const f32x4*)(b3 + jb);
    } else {
        bf8_t z = {0, 0, 0, 0, 0, 0, 0, 0};
#pragma unroll
        for (int c = 0; c < 4; ++c) A3[c] = z;
    }
    const f32x4 b1f = *(const f32x4*)(b1 + jb);
    const f32x4 b2f = *(const f32x4*)(b2 + jb);

    // phase-A / E mapping: e = wave, d = lane.  hi -> col=wave, lo -> col=wave+8 (+64 shorts).
    const int aidx = (lane >> 5) * CH + ((lane >> 3) & 3) * BLKS + wave * 8 + (lane & 7);
    const int elem = blockIdx.x * 8 + wave;

    // epilogue mapping: lane (quad, col) handles elem (col&7),
    // rows {4*quad + 2*(col>>3), +1} (post-fold both lane halves hold the full result)
    const int esel  = col >> 3;
    const int eelem = col & 7;
    const int j0    = 16 * wave + 4 * quad + 2 * esel;
    const int epidx = (j0 >> 5) * CH + ((j0 >> 3) & 3) * BLKS + eelem * 8 + (j0 & 7);

    // B-read offset: full 16 distinct columns (8 hi + 8 lo)
    const int boff = quad * BLKS + col * 8;

    // single-chain gemm (pre-fold partial: cols e and e+8 sum to full product)
    auto gemm = [&](const bf8_t* A, const short* Bc, int nch) -> f32x4 {
        f32x4 a0 = {0.f, 0.f, 0.f, 0.f};
#pragma unroll
        for (int c = 0; c < nch; ++c) {
            bf8_t b = *(const bf8_t*)(Bc + c * CH + boff);
            a0 = __builtin_amdgcn_mfma_f32_16x16x32_bf16(A[c], b, a0, 0, 0, 0);
        }
        return a0;
    };

    // all-lane epilogue: fold hi/lo columns (ALL regs, then select), softplus,
    // split back to hi/lo bf16 and store both column groups.
    auto epi = [&](f32x4 s, f32x4 bias, short* Bn) {
        float t0 = fold8(s[0]) + bias[0];
        float t1 = fold8(s[1]) + bias[1];
        float t2 = fold8(s[2]) + bias[2];
        float t3 = fold8(s[3]) + bias[3];
        float x0 = esel ? t2 : t0;
        float x1 = esel ? t3 : t1;
        float p0 = softplus_f(x0), p1 = softplus_f(x1);
        short h0, l0, h1, l1;
        split2(p0, h0, l0);
        split2(p1, h1, l1);
        *(unsigned*)(Bn + epidx)      = pk(h0, h1);   // rows j0, j0+1 adjacent shorts
        *(unsigned*)(Bn + epidx + 64) = pk(l0, l1);   // lo column group (col+8)
    };

    // one full MLP eval for all 8 elems; args must already be in argB
    auto eval = [&]() {
        __syncthreads();
        f32x4 s1 = gemm(A1, argB, 2);
        epi(s1, b1f, h1B);
        __syncthreads();
        f32x4 s2 = gemm(A2, h1B, 4);
        epi(s2, b2f, h2B);
        __syncthreads();
        if (wave < 4) {
            f32x4 s3 = gemm(A3, h2B, 4);
            f32x4 kv;
#pragma unroll
            for (int r = 0; r < 4; ++r) kv[r] = fold8(s3[r]) + b3f[r];
            if (col < 8) *(f32x4*)(kcur + col * 68 + jb) = kv;
        }
        __syncthreads();
    };

    // ---- state (per wave = per element; lane = dim) ----
    float y  = history[((size_t)elem * 15 + 14) * 64 + lane];
    float dt = 0.1f;
    float k1, k2, k3, k4, k5, k6;

    // initial k1 = f(y)  (FSAL thereafter)
    {
        short hi, lo; split2(y, hi, lo);
        argB[aidx] = hi; argB[aidx + 64] = lo;
        eval();
        k1 = kcur[wave * 68 + lane];
    }

#pragma unroll 1
    for (int seg = 1; seg <= NSEG; ++seg) {
        const float t1 = (float)seg;
        float t = t1 - 1.0f;
        bool done = false;

#pragma unroll 1
        for (int it = 0; it < MAXIT; ++it) {
            const float dt_c = fminf(dt, t1 - t);
            const float h = dt_c;
            float y5v = 0.f, k7v = 0.f;

#pragma unroll 1
            for (int st = 2; st <= 7; ++st) {
                float sum;
                switch (st) {
                    case 2: sum = cA21 * k1; break;
                    case 3: sum = fmaf(cA31, k1, cA32 * k2); break;
                    case 4: sum = fmaf(cA41, k1, fmaf(cA42, k2, cA43 * k3)); break;
                    case 5: sum = fmaf(cA51, k1, fmaf(cA52, k2, fmaf(cA53, k3, cA54 * k4))); break;
                    case 6: sum = fmaf(cA61, k1, fmaf(cA62, k2, fmaf(cA63, k3, fmaf(cA64, k4, cA65 * k5)))); break;
                    default: sum = fmaf(cB1, k1, fmaf(cB2, k2, fmaf(cB3, k3, fmaf(cB4, k4, fmaf(cB5, k5, cB6 * k6))))); break;
                }
                float arg = fmaf(h, sum, y);
                if (st == 7) y5v = arg;
                short hi, lo; split2(arg, hi, lo);
                argB[aidx] = hi; argB[aidx + 64] = lo;
                eval();
                float kv = kcur[wave * 68 + lane];
                switch (st) {
                    case 2: k2 = kv; break;
                    case 3: k3 = kv; break;
                    case 4: k4 = kv; break;
                    case 5: k5 = kv; break;
                    case 6: k6 = kv; break;
                    default: k7v = kv; break;
                }
            }

            // error norm (wave = one element, lanes = dims)
            float esum = fmaf(cE1, k1, fmaf(cE2, k2, fmaf(cE3, k3,
                         fmaf(cE4, k4, fmaf(cE5, k5, fmaf(cE6, k6, cE7 * k7v))))));
            float err = h * esum;
            float sc = fmaf(1e-3f, fmaxf(fabsf(y), fabsf(y5v)), 1e-6f);
            float r = err / sc;
            float rr = r * r;
#pragma unroll
            for (int off = 32; off > 0; off >>= 1) rr += __shfl_xor(rr, off, 64);
            float en = sqrtf(rr * (1.0f / 64.0f));

            bool accept = (en <= 1.0f) && !done;
            float fac = 0.9f * exp2f(-0.2f * log2f(fmaxf(en, 1e-10f)));
            fac = fminf(fmaxf(fac, 0.2f), 10.0f);

            if (accept) { t += dt_c; y = y5v; k1 = k7v; }   // FSAL: f(y_new) = k7
            if (!done) dt = dt_c * fac;
            done = done || (t >= t1 - 1e-8f);

            if (lane == 0) doneF[wave] = done ? 1 : 0;
            __syncthreads();
            bool all = true;
#pragma unroll
            for (int e2 = 0; e2 < 8; ++e2) all = all && (doneF[e2] != 0);
            if (all) break;
        }

        out[((size_t)elem * NSEG + (seg - 1)) * 64 + lane] = y;
    }
}

extern "C" void kernel_launch(void* const* d_in, const int* in_sizes, int n_in,
                              void* d_out, int out_size, void* d_ws, size_t ws_size,
                              hipStream_t stream) {
    const float* history = (const float*)d_in[0];
    const float* W1 = (const float*)d_in[1];
    const float* b1 = (const float*)d_in[2];
    const float* W2 = (const float*)d_in[3];
    const float* b2 = (const float*)d_in[4];
    const float* W3 = (const float*)d_in[5];
    const float* b3 = (const float*)d_in[6];
    float* out = (float*)d_out;

    ode_kernel<<<dim3(NB / 8), dim3(512), 0, stream>>>(history, W1, b1, W2, b2, W3, b3, out);
}

// Round 12
// 278.023 us; speedup vs baseline: 1.0729x; 1.0729x over previous
//
#include <hip/hip_runtime.h>
#include <math.h>

#define NB    2048
#define NSEG  20
#define MAXIT 48
// LDS chunk layout: one 32-k chunk = 4 octet-blocks of BLKS shorts.
// BLKS = 128 data shorts (16 cols x 8 k) + 8 pad shorts = 136.
// cols 0..7 = bf16-hi of elems 0..7, cols 8..15 = bf16-lo of elems 0..7.
// Bank math: BLKS*2B = 272B = 68 dwords == 4 (mod 32); chunk stride 544*2/4 = 272 == 16 (mod 32).
#define CH    544
#define BLKS  136

typedef __attribute__((ext_vector_type(8))) short bf8_t;
typedef __attribute__((ext_vector_type(4))) float f32x4;

#define cA21 ((float)0.161)
#define cA31 ((float)-0.008480655492356989)
#define cA32 ((float)0.335480655492357)
#define cA41 ((float)2.8971530571054935)
#define cA42 ((float)-6.359448489975075)
#define cA43 ((float)4.3622954328695815)
#define cA51 ((float)5.325864828439257)
#define cA52 ((float)-11.748883564062828)
#define cA53 ((float)7.4955393428898365)
#define cA54 ((float)-0.09249506636175525)
#define cA61 ((float)5.86145544294642)
#define cA62 ((float)-12.92096931784711)
#define cA63 ((float)8.159367898576159)
#define cA64 ((float)-0.071584973281401)
#define cA65 ((float)-0.028269050394068383)
#define cB1  ((float)0.09646076681806523)
#define cB2  ((float)0.01)
#define cB3  ((float)0.4798896504144996)
#define cB4  ((float)1.379008574103742)
#define cB5  ((float)-3.290069515436081)
#define cB6  ((float)2.324710524099774)
#define cE1  ((float)-0.001780011052225777)
#define cE2  ((float)-0.0008164344596567469)
#define cE3  ((float)0.007880878010261995)
#define cE4  ((float)-0.1447110071732629)
#define cE5  ((float)0.5823571654525552)
#define cE6  ((float)-0.45808210592918697)
#define cE7  ((float)0.015151515151515152)

__device__ __forceinline__ void split2(float x, short &hi, short &lo) {
    // x ~= bf16(hi) + bf16(lo), truncation-based (x - hi is exact in fp32)
    unsigned u = __float_as_uint(x);
    hi = (short)(u >> 16);
    float r = x - __uint_as_float(u & 0xFFFF0000u);
    lo = (short)(__float_as_uint(r) >> 16);
}

__device__ __forceinline__ float softplus_f(float x) {
    float t = exp2f(-fabsf(x) * 1.442695040888963f);
    return fmaxf(x, 0.0f) + log2f(1.0f + t) * 0.6931471805599453f;
}

__device__ __forceinline__ unsigned pk(short a, short b) {
    return ((unsigned)(unsigned short)a) | (((unsigned)(unsigned short)b) << 16);
}

// x + (x from lane^8 within each 16-lane row): DPP row_ror:8 (0x128) is an
// 8-rotation within 16 lanes == xor-8 swap. Pure VALU, no LDS pipe.
// NOTE: must be applied BEFORE any esel-dependent register select — both
// lane halves must fold the SAME register (round-4 bug).
__device__ __forceinline__ float fold8(float x) {
    int r = __builtin_amdgcn_update_dpp(__float_as_int(x), __float_as_int(x),
                                        0x128, 0xF, 0xF, false);
    return x + __int_as_float(r);
}

// 512 threads = 8 waves; block processes 8 elements in lockstep.
// Weights live in per-lane MFMA A-fragments (bf16 hi/lo) for the whole kernel.
// Acts ping-pong through LDS in MFMA B-fragment layout with hi/lo packed into
// the 16 columns: col e = hi(elem e), col e+8 = lo(elem e).  Two MFMAs/chunk
// (independent accumulator chains — r11 showed the pair's pipelining is
// load-bearing).  RK state lives in the MFMA D-layout on waves 0-3: lane
// (quad q, col c) of wave w owns dims d0=16w+4q+2*(c>>3)+{0,1} of elem c&7.
// Layer-3 output is consumed in-register (no kcur LDS round-trip, no post-L3
// barrier).  Waves 4-7 are pure GEMM workers (deterministic replicas of the
// scalar dt/t/done logic from shared rrP partials).
// Frag-layout (16x16x32 bf16): A[m=lane&15][k=32c+8*quad+jj]; B[k][n=lane&15];
// C/D: col=lane&15, row=4*quad+reg  (m89-verified).
//
// Session conclusion (r0-r11): this structure sits at its cross-wave-relayout
// latency floor (~228 us counter).  Probed and rejected: barrier count (r5),
// 2 blocks/CU (r6), VALU trims (r7), z-space phase elimination (r8/r9),
// async controller (r10 — zero lockstep waste, conflicts bit-identical),
// single-MFMA chains (r11 — chain depth regression).
__global__ __launch_bounds__(512)
void ode_kernel(const float* __restrict__ history,
                const float* __restrict__ W1, const float* __restrict__ b1,
                const float* __restrict__ W2, const float* __restrict__ b2,
                const float* __restrict__ W3, const float* __restrict__ b3,
                float* __restrict__ out)
{
    __shared__ alignas(16) short argB[2 * CH];
    __shared__ alignas(16) short h1B[4 * CH];
    __shared__ alignas(16) short h2B[4 * CH];
    __shared__ float rrP[32];   // [wave<4][elem] error-norm partials

    const int tid  = threadIdx.x;
    const int wave = tid >> 6, lane = tid & 63;
    const int quad = lane >> 4, col = lane & 15;
    const int jb   = 16 * wave + 4 * quad;       // this lane's D-row base (j)

    // ---- preload weight A-fragments (bf16 hi/lo) ----
    bf8_t A1h[2], A1l[2], A2h[4], A2l[4], A3h[4], A3l[4];
#pragma unroll
    for (int c = 0; c < 2; ++c) {
        const float* p = W1 + (size_t)(16 * wave + col) * 64 + 32 * c + 8 * quad;
        bf8_t h, l;
#pragma unroll
        for (int j = 0; j < 8; ++j) { short hs, ls; split2(p[j], hs, ls); h[j] = hs; l[j] = ls; }
        A1h[c] = h; A1l[c] = l;
    }
#pragma unroll
    for (int c = 0; c < 4; ++c) {
        const float* p = W2 + (size_t)(16 * wave + col) * 128 + 32 * c + 8 * quad;
        bf8_t h, l;
#pragma unroll
        for (int j = 0; j < 8; ++j) { short hs, ls; split2(p[j], hs, ls); h[j] = hs; l[j] = ls; }
        A2h[c] = h; A2l[c] = l;
    }
    // state mapping (waves 0-3): esel splits the 4 D-rows into two 2-row halves
    const int esel = col >> 3;
    const int e    = col & 7;
    const int d0   = 16 * wave + 4 * quad + 2 * esel;   // meaningful for wave<4
    const size_t elemIdx = (size_t)(blockIdx.x * 8 + e);

    float b3v0 = 0.f, b3v1 = 0.f;
    if (wave < 4) {
#pragma unroll
        for (int c = 0; c < 4; ++c) {
            const float* p = W3 + (size_t)(16 * wave + col) * 128 + 32 * c + 8 * quad;
            bf8_t h, l;
#pragma unroll
            for (int j = 0; j < 8; ++j) { short hs, ls; split2(p[j], hs, ls); h[j] = hs; l[j] = ls; }
            A3h[c] = h; A3l[c] = l;
        }
        b3v0 = b3[d0]; b3v1 = b3[d0 + 1];
    } else {
        bf8_t z = {0, 0, 0, 0, 0, 0, 0, 0};
#pragma unroll
        for (int c = 0; c < 4; ++c) { A3h[c] = z; A3l[c] = z; }
    }
    const f32x4 b1f = *(const f32x4*)(b1 + jb);
    const f32x4 b2f = *(const f32x4*)(b2 + jb);

    // arg-write index (waves 0-3): same formula as epidx, rows = dims 0..63
    const int ai = (d0 >> 5) * CH + ((d0 >> 3) & 3) * BLKS + e * 8 + (d0 & 7);

    // epilogue mapping: lane (quad, col) handles elem col&7, rows j0, j0+1
    const int j0    = 16 * wave + 4 * quad + 2 * esel;
    const int epidx = (j0 >> 5) * CH + ((j0 >> 3) & 3) * BLKS + e * 8 + (j0 & 7);

    // B-read offset: full 16 distinct columns (8 hi + 8 lo)
    const int boff = quad * BLKS + col * 8;

    // returns per-reg sum of the two accumulator chains (pre-fold)
    auto gemm = [&](const bf8_t* Ah, const bf8_t* Al, const short* Bc, int nch) -> f32x4 {
        f32x4 a0 = {0.f, 0.f, 0.f, 0.f}, a1 = a0;
#pragma unroll
        for (int c = 0; c < nch; ++c) {
            bf8_t b = *(const bf8_t*)(Bc + c * CH + boff);
            a0 = __builtin_amdgcn_mfma_f32_16x16x32_bf16(Ah[c], b, a0, 0, 0, 0);
            a1 = __builtin_amdgcn_mfma_f32_16x16x32_bf16(Al[c], b, a1, 0, 0, 0);
        }
        f32x4 s;
#pragma unroll
        for (int r = 0; r < 4; ++r) s[r] = a0[r] + a1[r];
        return s;
    };

    // all-lane epilogue: fold hi/lo columns (ALL regs, then select), softplus,
    // split back to hi/lo bf16 and store both column groups.
    auto epi = [&](f32x4 s, f32x4 bias, short* Bn) {
        float t0 = fold8(s[0]) + bias[0];
        float t1 = fold8(s[1]) + bias[1];
        float t2 = fold8(s[2]) + bias[2];
        float t3 = fold8(s[3]) + bias[3];
        float x0 = esel ? t2 : t0;
        float x1 = esel ? t3 : t1;
        float p0 = softplus_f(x0), p1 = softplus_f(x1);
        short h0, l0, h1, l1;
        split2(p0, h0, l0);
        split2(p1, h1, l1);
        *(unsigned*)(Bn + epidx)      = pk(h0, h1);   // rows j0, j0+1 adjacent shorts
        *(unsigned*)(Bn + epidx + 64) = pk(l0, l1);   // lo column group (col+8)
    };

    // one full MLP eval; args must already be in argB.  L3 result (this lane's
    // 2 dims) returned in kv0/kv1 for waves 0-3.  3 barriers, no trailing one.
    auto eval = [&](float &kv0, float &kv1) {
        __syncthreads();
        f32x4 s1 = gemm(A1h, A1l, argB, 2);
        epi(s1, b1f, h1B);
        __syncthreads();
        f32x4 s2 = gemm(A2h, A2l, h1B, 4);
        epi(s2, b2f, h2B);
        __syncthreads();
        if (wave < 4) {
            f32x4 s3 = gemm(A3h, A3l, h2B, 4);
            // fold FIRST (both lane halves fold the same register), select after
            float f0 = fold8(s3[0]);
            float f1 = fold8(s3[1]);
            float f2 = fold8(s3[2]);
            float f3 = fold8(s3[3]);
            kv0 = (esel ? f2 : f0) + b3v0;
            kv1 = (esel ? f3 : f1) + b3v1;
        }
    };

    // ---- state (waves 0-3, D-layout): 2 dims per lane ----
    float y0 = 0.f, y1 = 0.f;
    float dt = 0.1f;              // tracked by ALL waves (deterministic replicas)
    float k1a = 0.f, k1b = 0.f, k2a, k2b, k3a, k3b, k4a, k4b, k5a, k5b, k6a, k6b;

    // initial k1 = f(y)  (FSAL thereafter)
    if (wave < 4) {
        float2 yy = *(const float2*)(history + (elemIdx * 15 + 14) * 64 + d0);
        y0 = yy.x; y1 = yy.y;
        short h0, l0, h1, l1;
        split2(y0, h0, l0); split2(y1, h1, l1);
        *(unsigned*)(argB + ai)      = pk(h0, h1);
        *(unsigned*)(argB + ai + 64) = pk(l0, l1);
    }
    eval(k1a, k1b);

#pragma unroll 1
    for (int seg = 1; seg <= NSEG; ++seg) {
        const float t1 = (float)seg;
        float t = t1 - 1.0f;
        bool done = false;

#pragma unroll 1
        for (int it = 0; it < MAXIT; ++it) {
            const float dt_c = fminf(dt, t1 - t);
            const float h = dt_c;
            float y50 = 0.f, y51 = 0.f, k7a = 0.f, k7b = 0.f;

#pragma unroll 1
            for (int st = 2; st <= 7; ++st) {
                if (wave < 4) {
                    float sum0, sum1;
                    switch (st) {
                        case 2: sum0 = cA21 * k1a;
                                sum1 = cA21 * k1b; break;
                        case 3: sum0 = fmaf(cA31, k1a, cA32 * k2a);
                                sum1 = fmaf(cA31, k1b, cA32 * k2b); break;
                        case 4: sum0 = fmaf(cA41, k1a, fmaf(cA42, k2a, cA43 * k3a));
                                sum1 = fmaf(cA41, k1b, fmaf(cA42, k2b, cA43 * k3b)); break;
                        case 5: sum0 = fmaf(cA51, k1a, fmaf(cA52, k2a, fmaf(cA53, k3a, cA54 * k4a)));
                                sum1 = fmaf(cA51, k1b, fmaf(cA52, k2b, fmaf(cA53, k3b, cA54 * k4b))); break;
                        case 6: sum0 = fmaf(cA61, k1a, fmaf(cA62, k2a, fmaf(cA63, k3a, fmaf(cA64, k4a, cA65 * k5a))));
                                sum1 = fmaf(cA61, k1b, fmaf(cA62, k2b, fmaf(cA63, k3b, fmaf(cA64, k4b, cA65 * k5b)))); break;
                        default: sum0 = fmaf(cB1, k1a, fmaf(cB2, k2a, fmaf(cB3, k3a, fmaf(cB4, k4a, fmaf(cB5, k5a, cB6 * k6a)))));
                                 sum1 = fmaf(cB1, k1b, fmaf(cB2, k2b, fmaf(cB3, k3b, fmaf(cB4, k4b, fmaf(cB5, k5b, cB6 * k6b))))); break;
                    }
                    float arg0 = fmaf(h, sum0, y0);
                    float arg1 = fmaf(h, sum1, y1);
                    if (st == 7) { y50 = arg0; y51 = arg1; }
                    short h0, l0, h1, l1;
                    split2(arg0, h0, l0); split2(arg1, h1, l1);
                    *(unsigned*)(argB + ai)      = pk(h0, h1);
                    *(unsigned*)(argB + ai + 64) = pk(l0, l1);
                }
                float kv0 = 0.f, kv1 = 0.f;
                eval(kv0, kv1);
                if (wave < 4) {
                    switch (st) {
                        case 2: k2a = kv0; k2b = kv1; break;
                        case 3: k3a = kv0; k3b = kv1; break;
                        case 4: k4a = kv0; k4b = kv1; break;
                        case 5: k5a = kv0; k5b = kv1; break;
                        case 6: k6a = kv0; k6b = kv1; break;
                        default: k7a = kv0; k7b = kv1; break;
                    }
                }
            }

            // error norm: per-lane 2-dim partial -> wave partial -> LDS -> all
            float rr2 = 0.f;
            if (wave < 4) {
                float es0 = fmaf(cE1, k1a, fmaf(cE2, k2a, fmaf(cE3, k3a,
                            fmaf(cE4, k4a, fmaf(cE5, k5a, fmaf(cE6, k6a, cE7 * k7a))))));
                float es1 = fmaf(cE1, k1b, fmaf(cE2, k2b, fmaf(cE3, k3b,
                            fmaf(cE4, k4b, fmaf(cE5, k5b, fmaf(cE6, k6b, cE7 * k7b))))));
                float err0 = h * es0, err1 = h * es1;
                float sc0 = fmaf(1e-3f, fmaxf(fabsf(y0), fabsf(y50)), 1e-6f);
                float sc1 = fmaf(1e-3f, fmaxf(fabsf(y1), fabsf(y51)), 1e-6f);
                float r0 = err0 / sc0, r1 = err1 / sc1;
                rr2 = fmaf(r0, r0, r1 * r1);
            }
            rr2 += __shfl_xor(rr2, 16, 64);   // sum quad bit0
            rr2 += __shfl_xor(rr2, 32, 64);   // sum quad bit1
            rr2 = fold8(rr2);                 // sum esel halves (symmetric, no select)
            if (wave < 4 && lane < 8) rrP[wave * 8 + lane] = rr2;  // lane = elem
            __syncthreads();
            float rs = ((rrP[e] + rrP[8 + e]) + rrP[16 + e]) + rrP[24 + e];
            float en = sqrtf(rs * (1.0f / 64.0f));

            bool accept = (en <= 1.0f) && !done;
            float fac = 0.9f * exp2f(-0.2f * log2f(fmaxf(en, 1e-10f)));
            fac = fminf(fmaxf(fac, 0.2f), 10.0f);

            if (wave < 4 && accept) { y0 = y50; y1 = y51; k1a = k7a; k1b = k7b; }  // FSAL
            if (accept) t += dt_c;
            if (!done) dt = dt_c * fac;
            done = done || (t >= t1 - 1e-8f);
            if (__all(done)) break;
        }

        if (wave < 4) {
            float2 yy; yy.x = y0; yy.y = y1;
            *(float2*)(out + (elemIdx * NSEG + (seg - 1)) * 64 + d0) = yy;
        }
    }
}

extern "C" void kernel_launch(void* const* d_in, const int* in_sizes, int n_in,
                              void* d_out, int out_size, void* d_ws, size_t ws_size,
                              hipStream_t stream) {
    const float* history = (const float*)d_in[0];
    const float* W1 = (const float*)d_in[1];
    const float* b1 = (const float*)d_in[2];
    const float* W2 = (const float*)d_in[3];
    const float* b2 = (const float*)d_in[4];
    const float* W3 = (const float*)d_in[5];
    const float* b3 = (const float*)d_in[6];
    float* out = (float*)d_out;

    ode_kernel<<<dim3(NB / 8), dim3(512), 0, stream>>>(history, W1, b1, W2, b2, W3, b3, out);
}